// Round 4
// baseline (271.504 us; speedup 1.0000x reference)
//
#include <hip/hip_runtime.h>
#include <math.h>

#define Bb 4
#define Hh 128
#define Ww 256
#define Cc 64
#define Ff 128
#define INH 130   // H+2
#define INW 258   // W+2

typedef __attribute__((ext_vector_type(8))) __bf16 bf16x8;
typedef __attribute__((ext_vector_type(4))) float floatx4;

__device__ __forceinline__ unsigned short f2bf(float f) {
  unsigned int u = __float_as_uint(f);
  unsigned int r = u + 0x7fffu + ((u >> 16) & 1u);   // RNE
  return (unsigned short)(r >> 16);
}

// v_cvt_pk_bf16_f32: D[15:0]=bf16(S0), D[31:16]=bf16(S1), RNE.
__device__ __forceinline__ unsigned int cvt_pk_bf16(float lo, float hi) {
  unsigned int r;
  asm("v_cvt_pk_bf16_f32 %0, %1, %2" : "=v"(r) : "v"(lo), "v"(hi));
  return r;
}

// ---------------------------------------------------------------------------
// Prep: kernel -> bf16 in MFMA-fragment order kTB[tap][kk][quad][f] (16B per
// (..,f) chunk -> B-frag loads are 16B/lane fully-coalesced), + fp64 offset
// table (fp32 would flip the ux>0 branch at h=0).
// ---------------------------------------------------------------------------
__global__ void prep_kernel(const float* __restrict__ kmat,
                            float* __restrict__ offtab,
                            unsigned short* __restrict__ kTB) {
  int gid = blockIdx.x * 256 + threadIdx.x;
  if (gid < 576 * 128) {
    int f = gid & 127;
    int k = gid >> 7;
    int tap = k >> 6;
    int r = k & 63;
    int kk = r >> 5;
    int quad = (r >> 3) & 3;
    int i = r & 7;
    int chunk = tap * 8 + kk * 4 + quad;
    kTB[((size_t)chunk * 128 + f) * 8 + i] = f2bf(kmat[gid]);
  }
  if (gid < Hh * 9) {
    int h = gid / 9;
    int j = gid - h * 9;
    const double pi = 3.14159265358979323846;
    double unit_w = 2.0 * pi / (double)Ww;
    double unit_h = pi / (2.0 * (double)Hh);
    double rho = tan(unit_w);
    double theta = ((double)(Ww / 2) - 0.5 * (double)Ww) * unit_w;
    double phi = ((double)Hh - (double)h) * unit_h;
    double cph = cos(phi), sph = sin(phi);
    double cth = cos(theta), sth = sin(theta);
    double pux = cph * cth, puy = sph, puz = cph * sth;
    double txx = puz, txy = 0.0, txz = -pux;
    double tyx = puy * txz - puz * txy;
    double tyy = puz * txx - pux * txz;
    double tyz = pux * txy - puy * txx;
    const int r0t[9] = {1, 1, 1, 0, 0, 0, -1, -1, -1};
    const int r1t[9] = {-1, 0, 1, -1, 0, 1, -1, 0, 1};
    auto proj = [&](int r0, int r1, double& xr, double& yr) {
      double ux = pux + rho * ((double)r0 * txx + (double)r1 * tyx);
      double uy = puy + rho * ((double)r0 * txy + (double)r1 * tyy);
      double uz = puz + rho * ((double)r0 * txz + (double)r1 * tyz);
      double base = atan2(uz, ux);
      double th;
      if (ux > 0.0)        th = base;
      else if (ux < 0.0)   th = (uz >= 0.0) ? base + pi : base - pi;
      else                 th = (uz > 0.0) ? pi * 0.5 : -pi * 0.5;
      double ph = asin(uy);
      xr = (th / pi + 1.0) * 0.5 * (double)Ww;
      yr = (1.0 - 2.0 * ph / pi) * (double)Hh;
    };
    double xc, yc, xj, yj;
    proj(0, 0, xc, yc);
    proj(r0t[j], r1t[j], xj, yj);
    offtab[gid * 2 + 0] = (float)(xj - xc);   // added to y (faithful swap)
    offtab[gid * 2 + 1] = (float)(yj - yc);   // added to x
  }
}

// ---------------------------------------------------------------------------
// Fused, BARRIER-FREE: per (b,h,128-w tile), 4 waves, m-split only (wave
// owns 32 w-rows x all 128 f). Each lane blends its OWN A-fragments in
// registers from its 4 bilinear corners (per-lane gather loads, L1/L2-hot;
// same FMA & line count as the LDS-fill scheme) -> zero LDS, zero
// __syncthreads, zero bank conflicts; waves fully independent, loads free
// to overlap MFMA across kk/mi/taps. Zero-pad semantics via weight masks
// (col outside [1,256] -> weight 0, address &255 in-bounds garbage) --
// identical to ref's zero-valued pad reads incl. the clamped-x1 corner.
// ---------------------------------------------------------------------------
__global__ __launch_bounds__(256, 3) void fused_kernel(
    const float* __restrict__ in, const float* __restrict__ bias,
    const unsigned short* __restrict__ kTB, const float* __restrict__ offtab,
    float* __restrict__ out) {
  // XCD swizzle: each XCD gets one b and a contiguous h-range (~4.4MB == L2)
  int lidx = ((blockIdx.x & 7) << 7) | (blockIdx.x >> 3);
  int wt = lidx & 1;
  int h  = (lidx >> 1) & 127;
  int b  = lidx >> 8;
  int w0 = wt << 7;

  int tid  = threadIdx.x;
  int lane = tid & 63;
  int wave = tid >> 6;
  int m_base = wave << 5;          // wave owns m 32*wave .. +31
  int l15  = lane & 15;
  int quad = lane >> 4;

  floatx4 acc[2][8];
#pragma unroll
  for (int i = 0; i < 2; i++)
#pragma unroll
    for (int j = 0; j < 8; j++) acc[i][j] = (floatx4){0.f, 0.f, 0.f, 0.f};

  const float* inb = in + (size_t)b * Hh * Ww * Cc;
  const bf16x8* kbase = (const bf16x8*)kTB;

  for (int tap = 0; tap < 9; tap++) {
    float off0 = offtab[(h * 9 + tap) * 2 + 0];
    float off1 = offtab[(h * 9 + tap) * 2 + 1];
    float dyk = (float)(tap / 3), dxk = (float)(tap % 3);

    // ---- y side (block-uniform): rows + weights, pad folded into weights ----
    float y = (float)h + dyk + off0;
    y = fminf(fmaxf(y, 0.f), (float)(INH - 1));
    int y0i = (int)floorf(y);
    int y1i = y0i + 1;
    y0i = min(max(y0i, 0), INH - 1);
    y1i = min(max(y1i, 0), INH - 1);
    float wy0 = (float)y1i - y;
    float wy1 = y - (float)y0i;
    if (!(y0i >= 1 && y0i <= Hh)) wy0 = 0.f;
    if (!(y1i >= 1 && y1i <= Hh)) wy1 = 0.f;
    const char* r0 = (const char*)(inb + (size_t)min(max(y0i - 1, 0), Hh - 1) * Ww * Cc);
    const char* r1 = (const char*)(inb + (size_t)min(max(y1i - 1, 0), Hh - 1) * Ww * Cc);

    // ---- x weights (block-uniform): frac(w + dxk + off1) is w-independent
    //      (wrap adds an integer), so q00..q11 shared by all lanes ----
    float xrep = (float)w0 + dxk + off1;
    float fr = xrep - floorf(xrep);
    float q00 = wy0 * (1.f - fr), q01 = wy0 * fr;
    float q10 = wy1 * (1.f - fr), q11 = wy1 * fr;

    // ---- per-lane bilinear column pair + masked weights ----
    int offc[2], offn[2];
    float w00[2], w01[2], w10[2], w11[2];
#pragma unroll
    for (int mi = 0; mi < 2; mi++) {
      int wout = m_base + mi * 16 + l15;
      float x = (float)(w0 + wout) + dxk + off1;   // ref op order
      if (x < 0.f) x += (float)INW;
      if (x > (float)(INW - 1)) x -= (float)INW;
      int c0 = (int)floorf(x);                      // [0,257]
      int c1 = min(c0 + 1, INW - 1);                // ref clips x1 to 257
      bool m0 = (unsigned)(c0 - 1) < (unsigned)Ww;  // col valid (non-pad)
      bool m1 = (unsigned)(c1 - 1) < (unsigned)Ww;
      offc[mi] = (((c0 - 1) & (Ww - 1)) << 8) + (quad << 5);
      offn[mi] = (((c1 - 1) & (Ww - 1)) << 8) + (quad << 5);
      w00[mi] = m0 ? q00 : 0.f;
      w01[mi] = m1 ? q01 : 0.f;
      w10[mi] = m0 ? q10 : 0.f;
      w11[mi] = m1 ? q11 : 0.f;
    }

#pragma unroll
    for (int kk = 0; kk < 2; kk++) {
      // B-frags: coalesced 16B/lane from L2-resident kTB
      int ch0 = (tap * 8 + kk * 4 + quad) * 128;
      bf16x8 bfrag[8];
#pragma unroll
      for (int ni = 0; ni < 8; ni++)
        bfrag[ni] = kbase[ch0 + ni * 16 + l15];

#pragma unroll
      for (int mi = 0; mi < 2; mi++) {
        int oc = offc[mi] + kk * 128;
        int on = offn[mi] + kk * 128;
        float4 a0l = *(const float4*)(r0 + oc);
        float4 a0h = *(const float4*)(r0 + oc + 16);
        float4 a1l = *(const float4*)(r0 + on);
        float4 a1h = *(const float4*)(r0 + on + 16);
        float4 b0l = *(const float4*)(r1 + oc);
        float4 b0h = *(const float4*)(r1 + oc + 16);
        float4 b1l = *(const float4*)(r1 + on);
        float4 b1h = *(const float4*)(r1 + on + 16);
        float W00 = w00[mi], W01 = w01[mi], W10 = w10[mi], W11 = w11[mi];
        float p0 = W00 * a0l.x + W01 * a1l.x + W10 * b0l.x + W11 * b1l.x;
        float p1 = W00 * a0l.y + W01 * a1l.y + W10 * b0l.y + W11 * b1l.y;
        float p2 = W00 * a0l.z + W01 * a1l.z + W10 * b0l.z + W11 * b1l.z;
        float p3 = W00 * a0l.w + W01 * a1l.w + W10 * b0l.w + W11 * b1l.w;
        float p4 = W00 * a0h.x + W01 * a1h.x + W10 * b0h.x + W11 * b1h.x;
        float p5 = W00 * a0h.y + W01 * a1h.y + W10 * b0h.y + W11 * b1h.y;
        float p6 = W00 * a0h.z + W01 * a1h.z + W10 * b0h.z + W11 * b1h.z;
        float p7 = W00 * a0h.w + W01 * a1h.w + W10 * b0h.w + W11 * b1h.w;
        union { uint4 u; bf16x8 v; } afc;
        afc.u.x = cvt_pk_bf16(p0, p1);
        afc.u.y = cvt_pk_bf16(p2, p3);
        afc.u.z = cvt_pk_bf16(p4, p5);
        afc.u.w = cvt_pk_bf16(p6, p7);
        bf16x8 af = afc.v;
#pragma unroll
        for (int ni = 0; ni < 8; ni++)
          acc[mi][ni] = __builtin_amdgcn_mfma_f32_16x16x32_bf16(
              af, bfrag[ni], acc[mi][ni], 0, 0, 0);
      }
    }
  }

  // ---- epilogue: bias + relu (C/D: col=lane&15, row=quad*4+r) ----
  size_t outbase = ((size_t)(b * Hh + h) * Ww + w0);
#pragma unroll
  for (int ni = 0; ni < 8; ni++) {
    int f = ni * 16 + l15;
    float bv = bias[f];
#pragma unroll
    for (int mi = 0; mi < 2; mi++) {
#pragma unroll
      for (int r = 0; r < 4; r++) {
        int m = m_base + mi * 16 + quad * 4 + r;
        out[(outbase + m) * Ff + f] = fmaxf(acc[mi][ni][r] + bv, 0.f);
      }
    }
  }
}

extern "C" void kernel_launch(void* const* d_in, const int* in_sizes, int n_in,
                              void* d_out, int out_size, void* d_ws, size_t ws_size,
                              hipStream_t stream) {
  const float* in   = (const float*)d_in[0];
  const float* kmat = (const float*)d_in[1];
  const float* bias = (const float*)d_in[2];
  float* out = (float*)d_out;

  float* offtab = (float*)d_ws;
  unsigned short* kTB = (unsigned short*)((char*)d_ws + Hh * 9 * 2 * sizeof(float));
  if (ws_size < (size_t)(Hh * 9 * 2 * sizeof(float) + 128 * 576 * sizeof(unsigned short)))
    return;

  prep_kernel<<<288, 256, 0, stream>>>(kmat, offtab, kTB);
  fused_kernel<<<Bb * Hh * (Ww / 128), 256, 0, stream>>>(in, bias, kTB, offtab, out);
}

// Round 5
// 156.456 us; speedup vs baseline: 1.7353x; 1.7353x over previous
//
#include <hip/hip_runtime.h>
#include <math.h>

#define Bb 4
#define Hh 128
#define Ww 256
#define Cc 64
#define Ff 128
#define INH 130   // H+2
#define INW 258   // W+2

#define WSLOT 72   // shorts per slot (64 + 8 pad): 144B stride, 16B-aligned
#define WPW 37     // slots per wave: 36 data (rows 32w..32w+35) + slot 36 = zero

typedef __attribute__((ext_vector_type(8))) __bf16 bf16x8;
typedef __attribute__((ext_vector_type(4))) float floatx4;

__device__ __forceinline__ unsigned short f2bf(float f) {
  unsigned int u = __float_as_uint(f);
  unsigned int r = u + 0x7fffu + ((u >> 16) & 1u);   // RNE
  return (unsigned short)(r >> 16);
}

// v_cvt_pk_bf16_f32: D[15:0]=bf16(S0), D[31:16]=bf16(S1), RNE.
__device__ __forceinline__ unsigned int cvt_pk_bf16(float lo, float hi) {
  unsigned int r;
  asm("v_cvt_pk_bf16_f32 %0, %1, %2" : "=v"(r) : "v"(lo), "v"(hi));
  return r;
}

// ---------------------------------------------------------------------------
// Prep: kernel -> bf16 in MFMA-fragment order kTB[tap][kk][quad][f] (16B per
// (..,f) chunk -> B-frag loads are 16B/lane fully-coalesced), + fp64 offset
// table (fp32 would flip the ux>0 branch at h=0).
// ---------------------------------------------------------------------------
__global__ void prep_kernel(const float* __restrict__ kmat,
                            float* __restrict__ offtab,
                            unsigned short* __restrict__ kTB) {
  int gid = blockIdx.x * 256 + threadIdx.x;
  if (gid < 576 * 128) {
    int f = gid & 127;
    int k = gid >> 7;
    int tap = k >> 6;
    int r = k & 63;
    int kk = r >> 5;
    int quad = (r >> 3) & 3;
    int i = r & 7;
    int chunk = tap * 8 + kk * 4 + quad;
    kTB[((size_t)chunk * 128 + f) * 8 + i] = f2bf(kmat[gid]);
  }
  if (gid < Hh * 9) {
    int h = gid / 9;
    int j = gid - h * 9;
    const double pi = 3.14159265358979323846;
    double unit_w = 2.0 * pi / (double)Ww;
    double unit_h = pi / (2.0 * (double)Hh);
    double rho = tan(unit_w);
    double theta = ((double)(Ww / 2) - 0.5 * (double)Ww) * unit_w;
    double phi = ((double)Hh - (double)h) * unit_h;
    double cph = cos(phi), sph = sin(phi);
    double cth = cos(theta), sth = sin(theta);
    double pux = cph * cth, puy = sph, puz = cph * sth;
    double txx = puz, txy = 0.0, txz = -pux;
    double tyx = puy * txz - puz * txy;
    double tyy = puz * txx - pux * txz;
    double tyz = pux * txy - puy * txx;
    const int r0t[9] = {1, 1, 1, 0, 0, 0, -1, -1, -1};
    const int r1t[9] = {-1, 0, 1, -1, 0, 1, -1, 0, 1};
    auto proj = [&](int r0, int r1, double& xr, double& yr) {
      double ux = pux + rho * ((double)r0 * txx + (double)r1 * tyx);
      double uy = puy + rho * ((double)r0 * txy + (double)r1 * tyy);
      double uz = puz + rho * ((double)r0 * txz + (double)r1 * tyz);
      double base = atan2(uz, ux);
      double th;
      if (ux > 0.0)        th = base;
      else if (ux < 0.0)   th = (uz >= 0.0) ? base + pi : base - pi;
      else                 th = (uz > 0.0) ? pi * 0.5 : -pi * 0.5;
      double ph = asin(uy);
      xr = (th / pi + 1.0) * 0.5 * (double)Ww;
      yr = (1.0 - 2.0 * ph / pi) * (double)Hh;
    };
    double xc, yc, xj, yj;
    proj(0, 0, xc, yc);
    proj(r0t[j], r1t[j], xj, yj);
    offtab[gid * 2 + 0] = (float)(xj - xc);   // added to y (faithful swap)
    offtab[gid * 2 + 1] = (float)(yj - yc);   // added to x
  }
}

// ---------------------------------------------------------------------------
// Fused, ZERO-BARRIER: per (b,h,128-w tile), 4 waves, pure m-split (wave w
// owns w-rows 32w..32w+31, all 128 f; acc[2][8]=64 AGPR). Each wave fills a
// PRIVATE premixed 36-slot window covering exactly the slots its A-frags
// read (slot = row+1, offsets are w-uniform; margin covers the ±1ulp floor
// jitter; anything else -> private zero slot). Fill keeps R2's coalesced
// shape (8 lanes x consecutive 32B of one column) -- R4 proved per-lane
// gather is a 64-line TA serialization. Same-wave DS ordering (in-order LDS
// pipe) replaces __syncthreads: write->read and read->overwrite hazards are
// program-ordered within a wave, so NO barrier and NO double buffer. Waves
// drift to independent phases; fill latency of one hides under another's
// MFMA, and tap t+1 global loads may hoist over tap t MFMA (no fence).
// ---------------------------------------------------------------------------
__global__ __launch_bounds__(256, 3) void fused_kernel(
    const float* __restrict__ in, const float* __restrict__ bias,
    const unsigned short* __restrict__ kTB, const float* __restrict__ offtab,
    float* __restrict__ out) {
  __shared__ unsigned short winH[4 * WPW * WSLOT];   // 21.3 KB, per-wave private

  // XCD swizzle: each XCD gets one b and a contiguous h-range (~4.4MB == L2)
  int lidx = ((blockIdx.x & 7) << 7) | (blockIdx.x >> 3);
  int wt = lidx & 1;
  int h  = (lidx >> 1) & 127;
  int b  = lidx >> 8;
  int w0 = wt << 7;

  int tid  = threadIdx.x;
  int lane = tid & 63;
  int wave = tid >> 6;
  int m_base = wave << 5;          // wave owns w-rows m_base .. m_base+31
  int l15  = lane & 15;
  int quad = lane >> 4;

  unsigned short* win = &winH[wave * (WPW * WSLOT)];
  // zero the private zero-slot (slot 36): 72 shorts = 144 B
  if (lane < 18) *(uint2*)&win[36 * WSLOT + lane * 4] = (uint2){0u, 0u};
  // no barrier: only this wave reads it; same-wave DS ops are in-order

  floatx4 acc[2][8];
#pragma unroll
  for (int i = 0; i < 2; i++)
#pragma unroll
    for (int j = 0; j < 8; j++) acc[i][j] = (floatx4){0.f, 0.f, 0.f, 0.f};

  const float* inb = in + (size_t)b * Hh * Ww * Cc;
  const bf16x8* kbase = (const bf16x8*)kTB;

  for (int tap = 0; tap < 9; tap++) {
    float off0 = offtab[(h * 9 + tap) * 2 + 0];
    float off1 = offtab[(h * 9 + tap) * 2 + 1];
    float dyk = (float)(tap / 3), dxk = (float)(tap % 3);

    // ---- y side (block-uniform): rows + weights, pad folded into weights ----
    float y = (float)h + dyk + off0;
    y = fminf(fmaxf(y, 0.f), (float)(INH - 1));
    int y0i = (int)floorf(y);
    int y1i = y0i + 1;
    y0i = min(max(y0i, 0), INH - 1);
    y1i = min(max(y1i, 0), INH - 1);
    float wy0 = (float)y1i - y;
    float wy1 = y - (float)y0i;
    if (!(y0i >= 1 && y0i <= Hh)) wy0 = 0.f;
    if (!(y1i >= 1 && y1i <= Hh)) wy1 = 0.f;
    const char* r0 = (const char*)(inb + (size_t)min(max(y0i - 1, 0), Hh - 1) * Ww * Cc);
    const char* r1 = (const char*)(inb + (size_t)min(max(y1i - 1, 0), Hh - 1) * Ww * Cc);

    // ---- x side: block-uniform fractional weights + window base ----
    float xrep = (float)w0 + dxk + off1;
    float flo  = floorf(xrep);
    int jb = (int)flo - 1;
    float fr = xrep - flo;              // uniform frac across w (±1ulp, benign)
    float q00 = wy0 * (1.f - fr), q01 = wy0 * fr;
    float q10 = wy1 * (1.f - fr), q11 = wy1 * fr;

    // ---- per-lane slots (local to this wave's window) ----
    int slotv[2];
#pragma unroll
    for (int mi = 0; mi < 2; mi++) {
      int wr = m_base + mi * 16 + l15;
      float x = (float)(w0 + wr) + dxk + off1;   // ref op order
      if (x < 0.f) x += (float)INW;
      if (x > (float)(INW - 1)) x -= (float)INW;
      int x0i = (int)floorf(x);
      int s = x0i - jb;
      if (s < 0) s += INW;              // single-wrap lanes -> mod lookup
      int ls = s - m_base;              // expected = (mi*16+l15)+1 in [1,33]
      if ((unsigned)ls > 35u) ls = 36;  // outside window -> private zero slot
      slotv[mi] = ls;
    }

    // ---- fill OWN window: 36 slots x 8 ch-groups = 288 tasks per wave;
    //      coalesced (8 lanes x consecutive 32B of one column) ----
    for (int it = 0; it < 5; it++) {
      int t = lane + (it << 6);
      if (t < 36 * 8) {
        int ls = t >> 3;
        int c8 = (t & 7) << 3;
        int col = jb + m_base + ls;             // global raw column
        if (col < 0) col += INW;
        if (col > INW - 1) col -= INW;          // col in [0,257]
        int ncol = (col == INW - 1) ? 0 : col + 1;   // == wrap(raw col+1)
        bool cok = ((unsigned)(col - 1) < (unsigned)Ww);
        bool nok = ((unsigned)(ncol - 1) < (unsigned)Ww);
        // masked lanes: address in-bounds garbage, weight 0
        unsigned offc = (((unsigned)((col - 1) & (Ww - 1))) << 8) + ((unsigned)c8 << 2);
        unsigned offn = (((unsigned)((ncol - 1) & (Ww - 1))) << 8) + ((unsigned)c8 << 2);
        float w00 = cok ? q00 : 0.f;
        float w01 = nok ? q01 : 0.f;
        float w10 = cok ? q10 : 0.f;
        float w11 = nok ? q11 : 0.f;
        uint4 st;
        {
          float4 a0 = *(const float4*)(r0 + offc);
          float4 a1 = *(const float4*)(r0 + offn);
          float4 b0 = *(const float4*)(r1 + offc);
          float4 b1 = *(const float4*)(r1 + offn);
          float px = w00 * a0.x + w01 * a1.x + w10 * b0.x + w11 * b1.x;
          float py = w00 * a0.y + w01 * a1.y + w10 * b0.y + w11 * b1.y;
          float pz = w00 * a0.z + w01 * a1.z + w10 * b0.z + w11 * b1.z;
          float pw = w00 * a0.w + w01 * a1.w + w10 * b0.w + w11 * b1.w;
          st.x = cvt_pk_bf16(px, py);
          st.y = cvt_pk_bf16(pz, pw);
        }
        {
          float4 a0 = *(const float4*)(r0 + offc + 16);
          float4 a1 = *(const float4*)(r0 + offn + 16);
          float4 b0 = *(const float4*)(r1 + offc + 16);
          float4 b1 = *(const float4*)(r1 + offn + 16);
          float px = w00 * a0.x + w01 * a1.x + w10 * b0.x + w11 * b1.x;
          float py = w00 * a0.y + w01 * a1.y + w10 * b0.y + w11 * b1.y;
          float pz = w00 * a0.z + w01 * a1.z + w10 * b0.z + w11 * b1.z;
          float pw = w00 * a0.w + w01 * a1.w + w10 * b0.w + w11 * b1.w;
          st.z = cvt_pk_bf16(px, py);
          st.w = cvt_pk_bf16(pz, pw);
        }
        *(uint4*)(&win[ls * WSLOT + c8]) = st;  // 16B-aligned ds_write_b128
      }
    }

    // ---- MFMA: A-frags from OWN window (in-order DS guarantees fill done);
    //      B-frags coalesced from L1-hot kTB, each feeds both mi ----
#pragma unroll
    for (int kk = 0; kk < 2; kk++) {
      int ch0 = (tap * 8 + kk * 4 + quad) * 128;
      bf16x8 af0 = *(const bf16x8*)&win[slotv[0] * WSLOT + kk * 32 + quad * 8];
      bf16x8 af1 = *(const bf16x8*)&win[slotv[1] * WSLOT + kk * 32 + quad * 8];
#pragma unroll
      for (int ni = 0; ni < 8; ni++) {
        bf16x8 bf = kbase[ch0 + ni * 16 + l15];
        acc[0][ni] = __builtin_amdgcn_mfma_f32_16x16x32_bf16(af0, bf, acc[0][ni], 0, 0, 0);
        acc[1][ni] = __builtin_amdgcn_mfma_f32_16x16x32_bf16(af1, bf, acc[1][ni], 0, 0, 0);
      }
    }
    // no barrier: next tap's fill overwrites only THIS wave's window after
    // this wave's reads (same-wave DS ops execute in issue order)
  }

  // ---- epilogue: bias + relu (C/D: col=lane&15, row=quad*4+r) ----
  size_t outbase = ((size_t)(b * Hh + h) * Ww + w0);
#pragma unroll
  for (int ni = 0; ni < 8; ni++) {
    int f = ni * 16 + l15;
    float bv = bias[f];
#pragma unroll
    for (int mi = 0; mi < 2; mi++) {
#pragma unroll
      for (int r = 0; r < 4; r++) {
        int m = m_base + mi * 16 + quad * 4 + r;
        out[(outbase + m) * Ff + f] = fmaxf(acc[mi][ni][r] + bv, 0.f);
      }
    }
  }
}

extern "C" void kernel_launch(void* const* d_in, const int* in_sizes, int n_in,
                              void* d_out, int out_size, void* d_ws, size_t ws_size,
                              hipStream_t stream) {
  const float* in   = (const float*)d_in[0];
  const float* kmat = (const float*)d_in[1];
  const float* bias = (const float*)d_in[2];
  float* out = (float*)d_out;

  float* offtab = (float*)d_ws;
  unsigned short* kTB = (unsigned short*)((char*)d_ws + Hh * 9 * 2 * sizeof(float));
  if (ws_size < (size_t)(Hh * 9 * 2 * sizeof(float) + 128 * 576 * sizeof(unsigned short)))
    return;

  prep_kernel<<<288, 256, 0, stream>>>(kmat, offtab, kTB);
  fused_kernel<<<Bb * Hh * (Ww / 128), 256, 0, stream>>>(in, bias, kTB, offtab, out);
}

// Round 6
// 136.647 us; speedup vs baseline: 1.9869x; 1.1450x over previous
//
#include <hip/hip_runtime.h>
#include <math.h>

#define Bb 4
#define Hh 128
#define Ww 256
#define Cc 64
#define Ff 128
#define INH 130   // H+2
#define INW 258   // W+2

#define YSTRIDE 68   // floats per slot (64 + 4 pad): 272B, 16B-aligned, bank-floor
#define YSLOTS 37    // slots/wave: 0..35 data (32 rows + margin), 36 = zero slot

typedef __attribute__((ext_vector_type(8))) __bf16 bf16x8;
typedef __attribute__((ext_vector_type(4))) float floatx4;

__device__ __forceinline__ unsigned short f2bf(float f) {
  unsigned int u = __float_as_uint(f);
  unsigned int r = u + 0x7fffu + ((u >> 16) & 1u);   // RNE
  return (unsigned short)(r >> 16);
}

// v_cvt_pk_bf16_f32: D[15:0]=bf16(S0), D[31:16]=bf16(S1), RNE.
__device__ __forceinline__ unsigned int cvt_pk_bf16(float lo, float hi) {
  unsigned int r;
  asm("v_cvt_pk_bf16_f32 %0, %1, %2" : "=v"(r) : "v"(lo), "v"(hi));
  return r;
}

// ---------------------------------------------------------------------------
// Prep: kernel -> bf16 in MFMA-fragment order kTB[tap][kk][quad][f] (16B per
// (..,f) chunk -> B-frag loads are 16B/lane fully-coalesced), + fp64 offset
// table (fp32 would flip the ux>0 branch at h=0).
// ---------------------------------------------------------------------------
__global__ void prep_kernel(const float* __restrict__ kmat,
                            float* __restrict__ offtab,
                            unsigned short* __restrict__ kTB) {
  int gid = blockIdx.x * 256 + threadIdx.x;
  if (gid < 576 * 128) {
    int f = gid & 127;
    int k = gid >> 7;
    int tap = k >> 6;
    int r = k & 63;
    int kk = r >> 5;
    int quad = (r >> 3) & 3;
    int i = r & 7;
    int chunk = tap * 8 + kk * 4 + quad;
    kTB[((size_t)chunk * 128 + f) * 8 + i] = f2bf(kmat[gid]);
  }
  if (gid < Hh * 9) {
    int h = gid / 9;
    int j = gid - h * 9;
    const double pi = 3.14159265358979323846;
    double unit_w = 2.0 * pi / (double)Ww;
    double unit_h = pi / (2.0 * (double)Hh);
    double rho = tan(unit_w);
    double theta = ((double)(Ww / 2) - 0.5 * (double)Ww) * unit_w;
    double phi = ((double)Hh - (double)h) * unit_h;
    double cph = cos(phi), sph = sin(phi);
    double cth = cos(theta), sth = sin(theta);
    double pux = cph * cth, puy = sph, puz = cph * sth;
    double txx = puz, txy = 0.0, txz = -pux;
    double tyx = puy * txz - puz * txy;
    double tyy = puz * txx - pux * txz;
    double tyz = pux * txy - puy * txx;
    const int r0t[9] = {1, 1, 1, 0, 0, 0, -1, -1, -1};
    const int r1t[9] = {-1, 0, 1, -1, 0, 1, -1, 0, 1};
    auto proj = [&](int r0, int r1, double& xr, double& yr) {
      double ux = pux + rho * ((double)r0 * txx + (double)r1 * tyx);
      double uy = puy + rho * ((double)r0 * txy + (double)r1 * tyy);
      double uz = puz + rho * ((double)r0 * txz + (double)r1 * tyz);
      double base = atan2(uz, ux);
      double th;
      if (ux > 0.0)        th = base;
      else if (ux < 0.0)   th = (uz >= 0.0) ? base + pi : base - pi;
      else                 th = (uz > 0.0) ? pi * 0.5 : -pi * 0.5;
      double ph = asin(uy);
      xr = (th / pi + 1.0) * 0.5 * (double)Ww;
      yr = (1.0 - 2.0 * ph / pi) * (double)Hh;
    };
    double xc, yc, xj, yj;
    proj(0, 0, xc, yc);
    proj(r0t[j], r1t[j], xj, yj);
    offtab[gid * 2 + 0] = (float)(xj - xc);   // added to y (faithful swap)
    offtab[gid * 2 + 1] = (float)(yj - yc);   // added to x
  }
}

// ---------------------------------------------------------------------------
// Fused, ZERO-BARRIER + SPLIT PREMIX: per (b,h,128-w tile), 4 waves, pure
// m-split (wave owns 32 w-rows, all 128 f). Fill stores the Y-BLEND ONLY
// (fp32, ONE column read per slot -> fill VMEM halved vs 4-corner premix;
// L1-return bandwidth is the measured binding resource R2/R5). The x-blend
// (1-fr)*yb[s] + fr*yb[s+1] happens at A-frag read from LDS (off the L1
// path; stride-68 layout puts all accesses at the 8-lane/quad-bank floor =
// conflict-free). fp32 y-blend + fp32 x-blend + single RNE cvt = same
// rounding structure as the 4-corner premix. Private per-wave windows ->
// same-wave in-order DS replaces all __syncthreads (R5-proven skeleton).
// ---------------------------------------------------------------------------
__global__ __launch_bounds__(256, 4) void fused_kernel(
    const float* __restrict__ in, const float* __restrict__ bias,
    const unsigned short* __restrict__ kTB, const float* __restrict__ offtab,
    float* __restrict__ out) {
  __shared__ float ybH[4 * YSLOTS * YSTRIDE];   // 40,256 B -> 4 blocks/CU

  // XCD swizzle: each XCD gets one b and a contiguous h-range (~4.4MB == L2)
  int lidx = ((blockIdx.x & 7) << 7) | (blockIdx.x >> 3);
  int wt = lidx & 1;
  int h  = (lidx >> 1) & 127;
  int b  = lidx >> 8;
  int w0 = wt << 7;

  int tid  = threadIdx.x;
  int lane = tid & 63;
  int wave = tid >> 6;
  int m_base = wave << 5;          // wave owns w-rows m_base .. m_base+31
  int l15  = lane & 15;
  int quad = lane >> 4;

  float* yb = &ybH[wave * (YSLOTS * YSTRIDE)];
  // zero the private zero-slot (slot 36): 68 floats
  if (lane < 17) *(float4*)&yb[36 * YSTRIDE + lane * 4] = (float4){0.f, 0.f, 0.f, 0.f};
  // no barrier: only this wave reads it; same-wave DS ops are in-order

  floatx4 acc[2][8];
#pragma unroll
  for (int i = 0; i < 2; i++)
#pragma unroll
    for (int j = 0; j < 8; j++) acc[i][j] = (floatx4){0.f, 0.f, 0.f, 0.f};

  const float* inb = in + (size_t)b * Hh * Ww * Cc;
  const bf16x8* kbase = (const bf16x8*)kTB;

  for (int tap = 0; tap < 9; tap++) {
    float off0 = offtab[(h * 9 + tap) * 2 + 0];
    float off1 = offtab[(h * 9 + tap) * 2 + 1];
    float dyk = (float)(tap / 3), dxk = (float)(tap % 3);

    // ---- y side (block-uniform): rows + weights, pad folded into weights ----
    float y = (float)h + dyk + off0;
    y = fminf(fmaxf(y, 0.f), (float)(INH - 1));
    int y0i = (int)floorf(y);
    int y1i = y0i + 1;
    y0i = min(max(y0i, 0), INH - 1);
    y1i = min(max(y1i, 0), INH - 1);
    float wy0 = (float)y1i - y;
    float wy1 = y - (float)y0i;
    if (!(y0i >= 1 && y0i <= Hh)) wy0 = 0.f;
    if (!(y1i >= 1 && y1i <= Hh)) wy1 = 0.f;
    const char* r0 = (const char*)(inb + (size_t)min(max(y0i - 1, 0), Hh - 1) * Ww * Cc);
    const char* r1 = (const char*)(inb + (size_t)min(max(y1i - 1, 0), Hh - 1) * Ww * Cc);

    // ---- x side: block-uniform frac + window base ----
    float xrep = (float)w0 + dxk + off1;
    float flo  = floorf(xrep);
    int jb = (int)flo - 1;
    float fr = xrep - flo;              // uniform frac across w (±1ulp, benign)
    float fxa = 1.f - fr, fxb = fr;

    // ---- per-lane slot pairs (local to this wave's window) ----
    int s0v[2], s1v[2];
#pragma unroll
    for (int mi = 0; mi < 2; mi++) {
      int wr = m_base + mi * 16 + l15;
      float x = (float)(w0 + wr) + dxk + off1;   // ref op order
      if (x < 0.f) x += (float)INW;
      if (x > (float)(INW - 1)) x -= (float)INW;
      int x0i = (int)floorf(x);
      int s = x0i - jb;
      if (s < 0) s += INW;              // single-wrap lanes -> mod lookup
      int ls = s - m_base;              // expected = (mi*16+l15)+1 in [1,33]
      bool ok = (unsigned)ls <= 34u;    // margin for ±1ulp jitter
      s0v[mi] = ok ? ls : 36;           // outside window -> zero slot (both)
      s1v[mi] = ok ? ls + 1 : 36;
    }

    // ---- fill OWN window with Y-BLEND: 36 slots x 8 ch-groups = 288 tasks;
    //      coalesced (8 lanes x consecutive 32B of one column); ONE column
    //      read per slot (the ncol read is gone) ----
#pragma unroll
    for (int it = 0; it < 5; it++) {
      int t = lane + (it << 6);
      if (it < 4 || lane < 32) {        // 288 tasks
        int ls = t >> 3;
        int c8f = (t & 7) << 3;                 // float channel base
        int col = jb + m_base + ls;             // global raw column
        if (col < 0) col += INW;
        if (col > INW - 1) col -= INW;          // col in [0,257]
        bool cok = ((unsigned)(col - 1) < (unsigned)Ww);
        unsigned offc = (((unsigned)((col - 1) & (Ww - 1))) << 8) + ((unsigned)c8f << 2);
        float wa = cok ? wy0 : 0.f;             // x-pad -> zero column
        float wb = cok ? wy1 : 0.f;
        float4 a0 = *(const float4*)(r0 + offc);
        float4 a1 = *(const float4*)(r0 + offc + 16);
        float4 b0 = *(const float4*)(r1 + offc);
        float4 b1 = *(const float4*)(r1 + offc + 16);
        float4 p0, p1;
        p0.x = wa * a0.x + wb * b0.x;
        p0.y = wa * a0.y + wb * b0.y;
        p0.z = wa * a0.z + wb * b0.z;
        p0.w = wa * a0.w + wb * b0.w;
        p1.x = wa * a1.x + wb * b1.x;
        p1.y = wa * a1.y + wb * b1.y;
        p1.z = wa * a1.z + wb * b1.z;
        p1.w = wa * a1.w + wb * b1.w;
        float* dst = yb + ls * YSTRIDE + c8f;
        *(float4*)dst = p0;                     // 16B-aligned ds_write_b128
        *(float4*)(dst + 4) = p1;
      }
    }

    // ---- MFMA: A-frags x-blended from OWN window (in-order DS = fill done);
    //      B-frags coalesced from L1-hot kTB, each feeds both mi ----
#pragma unroll
    for (int kk = 0; kk < 2; kk++) {
      int ch0 = (tap * 8 + kk * 4 + quad) * 128;
      bf16x8 af[2];
#pragma unroll
      for (int mi = 0; mi < 2; mi++) {
        const float* pa = yb + s0v[mi] * YSTRIDE + kk * 32 + quad * 8;
        const float* pb = yb + s1v[mi] * YSTRIDE + kk * 32 + quad * 8;
        float4 ya = *(const float4*)pa;
        float4 yA = *(const float4*)(pa + 4);
        float4 yc = *(const float4*)pb;
        float4 yC = *(const float4*)(pb + 4);
        float p0 = fxa * ya.x + fxb * yc.x;
        float p1 = fxa * ya.y + fxb * yc.y;
        float p2 = fxa * ya.z + fxb * yc.z;
        float p3 = fxa * ya.w + fxb * yc.w;
        float p4 = fxa * yA.x + fxb * yC.x;
        float p5 = fxa * yA.y + fxb * yC.y;
        float p6 = fxa * yA.z + fxb * yC.z;
        float p7 = fxa * yA.w + fxb * yC.w;
        union { uint4 u; bf16x8 v; } afc;
        afc.u.x = cvt_pk_bf16(p0, p1);
        afc.u.y = cvt_pk_bf16(p2, p3);
        afc.u.z = cvt_pk_bf16(p4, p5);
        afc.u.w = cvt_pk_bf16(p6, p7);
        af[mi] = afc.v;
      }
#pragma unroll
      for (int ni = 0; ni < 8; ni++) {
        bf16x8 bf = kbase[ch0 + ni * 16 + l15];
        acc[0][ni] = __builtin_amdgcn_mfma_f32_16x16x32_bf16(af[0], bf, acc[0][ni], 0, 0, 0);
        acc[1][ni] = __builtin_amdgcn_mfma_f32_16x16x32_bf16(af[1], bf, acc[1][ni], 0, 0, 0);
      }
    }
    // no barrier: next tap's fill overwrites only THIS wave's window after
    // this wave's reads (same-wave DS ops execute in issue order)
  }

  // ---- epilogue: bias + relu (C/D: col=lane&15, row=quad*4+r) ----
  size_t outbase = ((size_t)(b * Hh + h) * Ww + w0);
#pragma unroll
  for (int ni = 0; ni < 8; ni++) {
    int f = ni * 16 + l15;
    float bv = bias[f];
#pragma unroll
    for (int mi = 0; mi < 2; mi++) {
#pragma unroll
      for (int r = 0; r < 4; r++) {
        int m = m_base + mi * 16 + quad * 4 + r;
        out[(outbase + m) * Ff + f] = fmaxf(acc[mi][ni][r] + bv, 0.f);
      }
    }
  }
}

extern "C" void kernel_launch(void* const* d_in, const int* in_sizes, int n_in,
                              void* d_out, int out_size, void* d_ws, size_t ws_size,
                              hipStream_t stream) {
  const float* in   = (const float*)d_in[0];
  const float* kmat = (const float*)d_in[1];
  const float* bias = (const float*)d_in[2];
  float* out = (float*)d_out;

  float* offtab = (float*)d_ws;
  unsigned short* kTB = (unsigned short*)((char*)d_ws + Hh * 9 * 2 * sizeof(float));
  if (ws_size < (size_t)(Hh * 9 * 2 * sizeof(float) + 128 * 576 * sizeof(unsigned short)))
    return;

  prep_kernel<<<288, 256, 0, stream>>>(kmat, offtab, kTB);
  fused_kernel<<<Bb * Hh * (Ww / 128), 256, 0, stream>>>(in, bias, kTB, offtab, out);
}